// Round 9
// baseline (204.325 us; speedup 1.0000x reference)
//
#include <hip/hip_runtime.h>
#include <cstdint>
#include <cstddef>

#define B_    8
#define N1_   1024
#define N2_   4096
#define C1_   256
#define C2_   128
#define CS_   64
#define CT_   448
#define H_    256
#define ROWS_ (B_ * N2_)   // 32768
#define XW_   192          // x2 row width: transposed [f2|skip] only

typedef __attribute__((ext_vector_type(8))) short bf16x8;
typedef __attribute__((ext_vector_type(4))) float f32x4;
typedef unsigned short ushort_t;
typedef unsigned int   uint_t;

__device__ __forceinline__ ushort_t f2bf(float f) {
    uint_t u = __float_as_uint(f);
    u = (u + 0x7fffu + ((u >> 16) & 1u)) >> 16;   // RNE
    return (ushort_t)u;
}
__device__ __forceinline__ float bf2f(ushort_t h) {
    return __uint_as_float(((uint_t)h) << 16);
}
// async global->LDS, 16B per lane; LDS dst = wave-uniform base + lane*16
__device__ __forceinline__ void glds16(const void* g, void* l) {
    __builtin_amdgcn_global_load_lds(
        (const __attribute__((address_space(1))) void*)g,
        (__attribute__((address_space(3))) void*)l, 16, 0, 0);
}

// XCD-affine tile decode (used by gemm2 only; neutral perf, kept).
__device__ __forceinline__ void tile_decode(int d, int& m0, int& n0) {
    const int j = d >> 3;
    m0 = ((d & 7) * 32 + (j >> 2)) * 128;
    n0 = (j & 3) * 64;
}

// ---------------------------------------------------------------- fused KNN + prep
// (unchanged — proven)
__global__ __launch_bounds__(256) void fused_pre(
    const float* __restrict__ p1, const float* __restrict__ p2,
    int* __restrict__ ind, float* __restrict__ wout,
    const float* __restrict__ f1, const float* __restrict__ f2,
    const float* __restrict__ fs, const float* __restrict__ W1,
    const float* __restrict__ W2, ushort_t* __restrict__ f1t,
    ushort_t* __restrict__ x, ushort_t* __restrict__ W1b, ushort_t* __restrict__ W2b)
{
#pragma clang fp contract(off)
    __shared__ __align__(16) char smem[32000];
    const int t = threadIdx.x;
    const int bid = blockIdx.x;
    if (bid < 1024) {
        float4*   cand  = (float4*)(smem);
        float*    pvals = (float*)(smem + 16512);
        float*    thr   = (float*)(smem + 19584);
        ushort_t* lists = (ushort_t*)(smem + 19712);
        float*    pdd   = (float*)(smem + 25856);
        int*      pdi   = (int*)(smem + 28928);
        const int b  = bid >> 7;
        const int qb = (bid & 127) * 32;
        const float* pb1 = p1 + (size_t)b * 3 * N1_;
        for (int i = t; i < N1_; i += 256) {
            float X = pb1[i], Y = pb1[N1_ + i], Z = pb1[2 * N1_ + i];
            cand[i] = make_float4(X, Y, Z, (X * X + Y * Y) + Z * Z);
        }
        const int q = t & 31, split = t >> 5;
        const int n = qb + q;
        const float* pb2 = p2 + (size_t)b * 3 * N2_;
        const float ax = pb2[n], ay = pb2[N2_ + n], az = pb2[2 * N2_ + n];
        const float s2a = (ax * ax + ay * ay) + az * az;
        const float m2x = -2.0f * ax, m2y = -2.0f * ay, m2z = -2.0f * az;
        __syncthreads();
        const int ibeg = split * 128, iend = ibeg + 128;
        {
            float a0 = 3e38f, a1 = 3e38f, a2 = 3e38f;
            for (int i = ibeg; i < iend; ++i) {
                float4 c = cand[i];
                float fd = fmaf(c.x, m2x, fmaf(c.y, m2y, fmaf(c.z, m2z, s2a + c.w)));
                float o0 = a0, o1 = a1;
                a0 = fminf(o0, fd);
                a1 = __builtin_amdgcn_fmed3f(fd, o0, o1);
                a2 = __builtin_amdgcn_fmed3f(fd, o1, a2);
            }
            pvals[t * 3 + 0] = a0; pvals[t * 3 + 1] = a1; pvals[t * 3 + 2] = a2;
        }
        __syncthreads();
        if (t < 32) {
            float m0 = 3e38f, m1 = 3e38f, m2v = 3e38f;
#pragma unroll
            for (int g = 0; g < 8; ++g)
#pragma unroll
                for (int r = 0; r < 3; ++r) {
                    float v = pvals[(g * 32 + t) * 3 + r];
                    float o0 = m0, o1 = m1;
                    m0 = fminf(o0, v);
                    m1 = __builtin_amdgcn_fmed3f(v, o0, o1);
                    m2v = __builtin_amdgcn_fmed3f(v, o1, m2v);
                }
            thr[t] = m2v + 2e-3f;
        }
        __syncthreads();
        const float th = thr[q];
        ushort_t* mylist = lists + (q * 8 + split) * 12;
        int cnt = 0;
        for (int i = ibeg; i < iend; ++i) {
            float4 c = cand[i];
            float fd = fmaf(c.x, m2x, fmaf(c.y, m2y, fmaf(c.z, m2z, s2a + c.w)));
            if (fd <= th && cnt < 12) { mylist[cnt] = (ushort_t)i; cnt++; }
        }
        float e0 = 3e38f, e1 = 3e38f, e2 = 3e38f;
        int   j0 = 0, j1 = 0, j2 = 0;
        for (int k = 0; k < cnt; ++k) {
            const int i = mylist[k];
            float4 c = cand[i];
            float dot = (ax * c.x + ay * c.y) + az * c.z;
            float dd  = (s2a + c.w) - 2.0f * dot;
            float d   = sqrtf(fmaxf(dd, 0.0f));
            if (d < e0)      { e2 = e1; j2 = j1; e1 = e0; j1 = j0; e0 = d; j0 = i; }
            else if (d < e1) { e2 = e1; j2 = j1; e1 = d;  j1 = i; }
            else if (d < e2) { e2 = d;  j2 = i; }
        }
        pdd[(split * 32 + q) * 3 + 0] = e0; pdi[(split * 32 + q) * 3 + 0] = j0;
        pdd[(split * 32 + q) * 3 + 1] = e1; pdi[(split * 32 + q) * 3 + 1] = j1;
        pdd[(split * 32 + q) * 3 + 2] = e2; pdi[(split * 32 + q) * 3 + 2] = j2;
        __syncthreads();
        if (t < 32) {
            float f0 = 3e38f, f1v = 3e38f, f2v = 3e38f;
            int   k0 = 0, k1 = 0, k2 = 0;
#pragma unroll
            for (int g = 0; g < 8; ++g)
#pragma unroll
                for (int r = 0; r < 3; ++r) {
                    float d = pdd[(g * 32 + t) * 3 + r];
                    int   i = pdi[(g * 32 + t) * 3 + r];
                    if (d < f0)       { f2v = f1v; k2 = k1; f1v = f0; k1 = k0; f0 = d; k0 = i; }
                    else if (d < f1v) { f2v = f1v; k2 = k1; f1v = d;  k1 = i; }
                    else if (d < f2v) { f2v = d;  k2 = i; }
                }
            float inv0 = 1.0f / (f0 + 1e-10f);
            float inv1 = 1.0f / (f1v + 1e-10f);
            float inv2 = 1.0f / (f2v + 1e-10f);
            float s = (inv0 + inv1) + inv2;
            const size_t row = (size_t)b * N2_ + qb + t;
            wout[row * 3 + 0] = inv0 / s;
            wout[row * 3 + 1] = inv1 / s;
            wout[row * 3 + 2] = inv2 / s;
            ind[row * 3 + 0] = k0;
            ind[row * 3 + 1] = k1;
            ind[row * 3 + 2] = k2;
        }
    } else if (bid < 1536) {
        float (*tile)[65] = (float (*)[65])smem;
        const int bid2 = bid - 1024;
        const int b  = bid2 >> 6;
        const int ct = (bid2 >> 4) & 3;
        const int nt = bid2 & 15;
        const int c0 = ct * 64, n0 = nt * 64;
        const float* src = f1 + ((size_t)b * C1_ + c0) * N1_ + n0;
#pragma unroll
        for (int j = 0; j < 16; ++j) {
            int lin = j * 256 + t;
            int ci = lin >> 6, nj = lin & 63;
            tile[ci][nj] = src[(size_t)ci * N1_ + nj];
        }
        __syncthreads();
        ushort_t* dst = f1t + ((size_t)b * N1_ + n0) * C1_ + c0;
#pragma unroll
        for (int j = 0; j < 8; ++j) {
            int lin = j * 256 + t;
            int ni = lin >> 5, cjp = (lin & 31) * 2;
            uint_t u = (uint_t)f2bf(tile[cjp][ni]) | ((uint_t)f2bf(tile[cjp + 1][ni]) << 16);
            *(uint_t*)&dst[(size_t)ni * C1_ + cjp] = u;
        }
    } else if (bid < 3072) {
        float (*tile)[65] = (float (*)[65])smem;
        const int bid2 = bid - 1536;
        const int b   = bid2 / 192;
        const int rem = bid2 - b * 192;
        const int ct  = rem >> 6;            // 0,1 -> f2 halves, 2 -> skip
        const int nt  = rem & 63;
        const float* src;
        if (ct < 2) src = f2 + ((size_t)b * C2_ + ct * 64) * N2_;
        else        src = fs + (size_t)b * CS_ * N2_;
        const int coff = ct * 64;            // column offset inside x2 (width 192)
        const int n0 = nt * 64;
#pragma unroll
        for (int j = 0; j < 16; ++j) {
            int lin = j * 256 + t;
            int ci = lin >> 6, nj = lin & 63;
            tile[ci][nj] = src[(size_t)ci * N2_ + n0 + nj];
        }
        __syncthreads();
#pragma unroll
        for (int j = 0; j < 8; ++j) {
            int lin = j * 256 + t;
            int ni = lin >> 5, cjp = (lin & 31) * 2;
            uint_t u = (uint_t)f2bf(tile[cjp][ni]) | ((uint_t)f2bf(tile[cjp + 1][ni]) << 16);
            *(uint_t*)&x[((size_t)b * N2_ + n0 + ni) * XW_ + coff + cjp] = u;
        }
    } else {
        const int i = (bid - 3072) * 256 + t;
        if (i < H_ * CT_) W1b[i] = f2bf(W1[i]);
        if (i < H_ * H_)  W2b[i] = f2bf(W2[i]);
    }
}

// ------------------------------- GEMM1, BM=64 x BN=256 @ 512 threads (8 waves).
// R8 post-mortem: B-staging traffic = (M/BM) x 229KB dominates; BM=32 doubled
// it (234 MB) and regressed. This keeps R7's joint-minimum tile (once-per-row
// gather, 117 MB B-staging) and fixes R7's actual limiter (2 blocks/CU) by
// doubling the block: grid 512, 40KB LDS, launch_bounds(512,6) -> 3 blocks/CU
// = 24 waves/CU. Per thread per K-step: 1 A-op + 4 B-glds (R8 had 1+8).
// Wave (wr,wc)=(wv&1,wv>>1) owns rows [wr*32,+32) x cols [wc*64,+64);
// acc[2][4] = 32 VGPR. Same swizzle algebra (slot = chunk ^ (row&7)); per-
// output K-order and MFMA sequence unchanged -> y1b bit-identical.
__global__ __launch_bounds__(512, 6) void gemm1_fused(
    const ushort_t* __restrict__ f1t, const int* __restrict__ ind,
    const float* __restrict__ wgt, const ushort_t* __restrict__ x2,
    const ushort_t* __restrict__ Bw, const float* __restrict__ bias,
    ushort_t* __restrict__ C, float* __restrict__ ssum, float* __restrict__ ssq)
{
    __shared__ __align__(16) ushort_t smem[20480];   // A 8KB + B 32KB = 40KB
    ushort_t* As = smem;            //  64 rows x 64 (128B rows, swizzled slots)
    ushort_t* Bs = smem + 4096;     // 256 rows x 64 (glds, swizzled slots)
    ushort_t* Cs = smem;            // epilogue reuse: 64 x 264 = 16896 shorts
    const int t = threadIdx.x;
    const int m0 = blockIdx.x * 64;
    const int lane = t & 63;
    const int wv = t >> 6;                             // 0..7
    const int wr = wv & 1;                             // row group (32 rows)
    const int wc = wv >> 1;                            // col group (64 cols)
    const int lm = lane & 15, lq = lane >> 4;
    const int lrow8  = lane >> 3;                      // 0..7
    const int lchunk = (lane & 7) ^ lrow8;             // swizzled source chunk
    const int aswz = lm & 7;                           // read-side row swizzle
    // B staging: 32 rows/wave, 4 glds16/thread/K-step
    const ushort_t* gB = Bw + (size_t)(wv * 32 + lrow8) * CT_ + lchunk * 8;
    ushort_t* lB = Bs + wv * 2048;
    // A glds staging (k0>=256): 8 rows/wave, 1 glds16/thread
    const ushort_t* gA = x2 + (size_t)(m0 + wv * 8 + lrow8) * XW_ + lchunk * 8;
    ushort_t* lA = As + wv * 512;
    // A interp staging (k0<256): 8 threads/row, 1 chunk (8 cols) each
    const int arow = t >> 3;                           // 0..63
    const int ac0  = t & 7;                            // chunk 0..7
    const size_t grow = (size_t)m0 + arow;
    const int bb_ = (int)(grow >> 12);                 // row / N2_
    const int* ip = ind + grow * 3;
    const float* wp = wgt + grow * 3;
    const ushort_t* fb = f1t + (size_t)bb_ * N1_ * C1_;
    const ushort_t* ga0 = fb + (size_t)ip[0] * C1_ + ac0 * 8;
    const ushort_t* ga1 = fb + (size_t)ip[1] * C1_ + ac0 * 8;
    const ushort_t* ga2 = fb + (size_t)ip[2] * C1_ + ac0 * 8;
    const float w0 = wp[0], w1 = wp[1], w2 = wp[2];
    ushort_t* awr = As + arow * 64;
    const int arsw = arow & 7;
    f32x4 acc[2][4];
#pragma unroll
    for (int i = 0; i < 2; ++i)
#pragma unroll
        for (int j = 0; j < 4; ++j)
            acc[i][j] = (f32x4){0.f, 0.f, 0.f, 0.f};

    for (int k0 = 0; k0 < CT_; k0 += 64) {
        __syncthreads();                  // previous iter's LDS reads complete
        if (k0 < 256) {
            uint4 va = *(const uint4*)(ga0 + k0);
            uint4 vb = *(const uint4*)(ga1 + k0);
            uint4 vc = *(const uint4*)(ga2 + k0);
            const uint_t* pa = (const uint_t*)&va;
            const uint_t* pb = (const uint_t*)&vb;
            const uint_t* pc = (const uint_t*)&vc;
            uint_t o[4];
#pragma unroll
            for (int e = 0; e < 4; ++e) {
                float lo = w0 * bf2f((ushort_t)(pa[e] & 0xffff))
                         + w1 * bf2f((ushort_t)(pb[e] & 0xffff))
                         + w2 * bf2f((ushort_t)(pc[e] & 0xffff));
                float hi = w0 * bf2f((ushort_t)(pa[e] >> 16))
                         + w1 * bf2f((ushort_t)(pb[e] >> 16))
                         + w2 * bf2f((ushort_t)(pc[e] >> 16));
                o[e] = (uint_t)f2bf(lo) | ((uint_t)f2bf(hi) << 16);
            }
            *(uint4*)&awr[(ac0 ^ arsw) * 8] = *(uint4*)o;
        } else {
            glds16(gA + (k0 - 256), lA);
        }
#pragma unroll
        for (int g = 0; g < 4; ++g)
            glds16(gB + k0 + g * 8 * CT_, lB + g * 512);
        __syncthreads();                  // drains vmcnt + lgkm -> tiles in LDS
#pragma unroll
        for (int h = 0; h < 2; ++h) {
            bf16x8 af[2], bfr[4];
#pragma unroll
            for (int i = 0; i < 2; ++i)
                af[i] = *(const bf16x8*)&As[(wr * 32 + i * 16 + lm) * 64
                                            + (((h * 4 + lq) ^ aswz)) * 8];
#pragma unroll
            for (int j = 0; j < 4; ++j)
                bfr[j] = *(const bf16x8*)&Bs[(wc * 64 + j * 16 + lm) * 64
                                             + (((h * 4 + lq) ^ aswz)) * 8];
#pragma unroll
            for (int i = 0; i < 2; ++i)
#pragma unroll
                for (int j = 0; j < 4; ++j)
                    acc[i][j] = __builtin_amdgcn_mfma_f32_16x16x32_bf16(af[i], bfr[j], acc[i][j], 0, 0, 0);
        }
    }
    __syncthreads();
#pragma unroll
    for (int j = 0; j < 4; ++j) {
        const int gn = wc * 64 + j * 16 + lm;          // global col (BN = H)
        const float bb = bias[gn];
        float ps = 0.0f, pq = 0.0f;
#pragma unroll
        for (int i = 0; i < 2; ++i) {
            const int row_l = wr * 32 + i * 16 + lq * 4;
            f32x4 v = acc[i][j];
#pragma unroll
            for (int r = 0; r < 4; ++r) {
                float val = v[r] + bb;
                ps += val;
                pq += val * val;
                float vo = __shfl_xor(val, 1);
                uint_t packed = (lm & 1)
                    ? ((uint_t)f2bf(vo)  | ((uint_t)f2bf(val) << 16))
                    : ((uint_t)f2bf(val) | ((uint_t)f2bf(vo)  << 16));
                if ((lm & 1) == 0)
                    *(uint_t*)&Cs[(row_l + r) * 264 + (gn & ~1)] = packed;
            }
        }
        ps += __shfl_xor(ps, 16); pq += __shfl_xor(pq, 16);
        ps += __shfl_xor(ps, 32); pq += __shfl_xor(pq, 32);
        if (lane < 16) {
            atomicAdd(&ssum[gn], ps);
            atomicAdd(&ssq[gn], pq);
        }
    }
    __syncthreads();
    const int srow = t >> 5;                           // 0..15
    const int scol = (t & 31) * 8;                     // 0..248
#pragma unroll
    for (int rep = 0; rep < 4; ++rep) {
        const int row = srow + rep * 16;
        uint4 v = *(const uint4*)&Cs[row * 264 + scol];
        *(uint4*)(C + (size_t)(m0 + row) * H_ + scol) = v;
    }
}

// ------------------------------- GEMM2: BK=64, BN1+ReLU fused A-staging
// (unchanged — R3-proven)
__global__ __launch_bounds__(256, 4) void gemm2_fused(
    const ushort_t* __restrict__ A, const ushort_t* __restrict__ Bw,
    const float* __restrict__ bias,
    const float* __restrict__ s1, const float* __restrict__ q1,
    const float* __restrict__ g1, const float* __restrict__ be1,
    ushort_t* __restrict__ C, float* __restrict__ ssum, float* __restrict__ ssq)
{
    __shared__ __align__(16) ushort_t smem[15360];   // 30.7 KB
    ushort_t* As0 = smem;                    // 128 x 40 padded (k-half 0)
    ushort_t* As1 = smem + 5120;             // 128 x 40 padded (k-half 1)
    ushort_t* Bs  = smem + 10240;            //  64 x 64 swizzled (glds)
    float*    sc  = (float*)(smem + 14336);  // 256 floats
    float*    sh  = (float*)(smem + 14848);  // 256 floats
    ushort_t* Cs  = smem;                    // epilogue reuse
    const int t = threadIdx.x;
    int m0, n0;
    tile_decode(blockIdx.x, m0, n0);
    const int lane = t & 63;
    const int wv = t >> 6;
    const int wrow = wv & 1, wcol = wv >> 1;
    const int lm = lane & 15, lq = lane >> 4;
    const int lrow8  = lane >> 3;
    const int lchunk = (lane & 7) ^ lrow8;
    const int aswz = lm & 7;
    const int arow = t >> 1, acol = (t & 1) * 32;     // A staging: 32 cols/thread
    {
        const float invN = 1.0f / (float)ROWS_;
        float mu  = s1[t] * invN;
        float var = q1[t] * invN - mu * mu;
        float s   = rsqrtf(var + 1e-3f) * g1[t];
        sc[t] = s;
        sh[t] = be1[t] - mu * s;
    }
    const ushort_t* gB = Bw + (size_t)(n0 + wv * 16 + lrow8) * H_ + lchunk * 8;
    ushort_t* lB = Bs + wv * 1024;
    const ushort_t* gA = A + (size_t)(m0 + arow) * H_ + acol;
    ushort_t* As_t = (t & 1) ? As1 : As0;
    f32x4 acc[4][2];
#pragma unroll
    for (int i = 0; i < 4; ++i)
#pragma unroll
        for (int j = 0; j < 2; ++j)
            acc[i][j] = (f32x4){0.f, 0.f, 0.f, 0.f};

    for (int k0 = 0; k0 < H_; k0 += 64) {
        uint4 av[4];
#pragma unroll
        for (int g = 0; g < 4; ++g)
            av[g] = *(const uint4*)(gA + k0 + g * 8);   // issued before barrier
        __syncthreads();                  // prev reads done; sc/sh visible (1st iter)
#pragma unroll
        for (int g = 0; g < 2; ++g)
            glds16(gB + k0 + g * 8 * H_, lB + g * 512);
#pragma unroll
        for (int g = 0; g < 4; ++g) {
            const uint_t* wsrc = (const uint_t*)&av[g];
            uint_t o[4];
#pragma unroll
            for (int e = 0; e < 4; ++e) {
                const int cb = k0 + acol + g * 8 + 2 * e;
                float lo = __uint_as_float(wsrc[e] << 16);
                float hi = __uint_as_float(wsrc[e] & 0xffff0000u);
                float r0 = fmaxf(fmaf(lo, sc[cb],     sh[cb]),     0.0f);
                float r1 = fmaxf(fmaf(hi, sc[cb + 1], sh[cb + 1]), 0.0f);
                o[e] = (uint_t)f2bf(r0) | ((uint_t)f2bf(r1) << 16);
            }
            *(uint4*)&As_t[arow * 40 + g * 8] = *(uint4*)o;
        }
        __syncthreads();                  // drains vmcnt (B) + lgkm (As)
#pragma unroll
        for (int h = 0; h < 2; ++h) {
            const ushort_t* Ah = h ? As1 : As0;
            bf16x8 af[4], bfr[2];
#pragma unroll
            for (int i = 0; i < 4; ++i)
                af[i] = *(const bf16x8*)&Ah[(wrow * 64 + i * 16 + lm) * 40 + lq * 8];
#pragma unroll
            for (int j = 0; j < 2; ++j)
                bfr[j] = *(const bf16x8*)&Bs[(wcol * 32 + j * 16 + lm) * 64
                                             + (((h * 4 + lq) ^ aswz)) * 8];
#pragma unroll
            for (int i = 0; i < 4; ++i)
#pragma unroll
                for (int j = 0; j < 2; ++j)
                    acc[i][j] = __builtin_amdgcn_mfma_f32_16x16x32_bf16(af[i], bfr[j], acc[i][j], 0, 0, 0);
        }
    }
    __syncthreads();
#pragma unroll
    for (int j = 0; j < 2; ++j) {
        const int gn_l = wcol * 32 + j * 16 + lm;
        const int gn   = n0 + gn_l;
        const float bb = bias[gn];
        float ps = 0.0f, pq = 0.0f;
#pragma unroll
        for (int i = 0; i < 4; ++i) {
            const int row_l = wrow * 64 + i * 16 + lq * 4;
            f32x4 v = acc[i][j];
#pragma unroll
            for (int r = 0; r < 4; ++r) {
                float val = v[r] + bb;
                ps += val;
                pq += val * val;
                float vo = __shfl_xor(val, 1);
                uint_t packed = (lm & 1)
                    ? ((uint_t)f2bf(vo)  | ((uint_t)f2bf(val) << 16))
                    : ((uint_t)f2bf(val) | ((uint_t)f2bf(vo)  << 16));
                if ((lm & 1) == 0)
                    *(uint_t*)&Cs[(row_l + r) * 72 + (gn_l & ~1)] = packed;
            }
        }
        ps += __shfl_xor(ps, 16); pq += __shfl_xor(pq, 16);
        ps += __shfl_xor(ps, 32); pq += __shfl_xor(pq, 32);
        if (lane < 16) {
            atomicAdd(&ssum[gn], ps);
            atomicAdd(&ssq[gn], pq);
        }
    }
    __syncthreads();
    const int srow = t >> 3;
    const int scol = (t & 7) * 8;
#pragma unroll
    for (int rep = 0; rep < 4; ++rep) {
        const int row = srow + rep * 32;
        uint4 v = *(const uint4*)&Cs[row * 72 + scol];
        *(uint4*)(C + (size_t)(m0 + row) * H_ + n0 + scol) = v;
    }
}

// ------------------------------- BN2 + ReLU + transpose (unchanged)
__global__ __launch_bounds__(256) void bn_out_kernel(
    const ushort_t* __restrict__ y, const float* __restrict__ ssum, const float* __restrict__ ssq,
    const float* __restrict__ g, const float* __restrict__ beta, float* __restrict__ out)
{
    __shared__ float tile[64][65];
    __shared__ float sc[64], sh[64];
    const float invN = 1.0f / (float)ROWS_;
    const int bid = blockIdx.x;
    const int b  = bid >> 8;
    const int nt = (bid >> 2) & 63;
    const int ot = bid & 3;
    const int t = threadIdx.x;
    if (t < 64) {
        int c = ot * 64 + t;
        float mu  = ssum[c] * invN;
        float var = ssq[c] * invN - mu * mu;
        float s   = rsqrtf(var + 1e-3f) * g[c];
        sc[t] = s;
        sh[t] = beta[c] - mu * s;
    }
    __syncthreads();
    const int n0 = nt * 64, o0 = ot * 64;
    const ushort_t* yb = y + ((size_t)b * N2_ + n0) * H_ + o0;
#pragma unroll
    for (int j = 0; j < 8; ++j) {
        int lin = j * 256 + t;
        int nl = lin >> 5, cu = (lin & 31) * 2;
        uint_t u = *(const uint_t*)&yb[(size_t)nl * H_ + cu];
        tile[nl][cu]     = fmaxf(bf2f((ushort_t)(u & 0xffff)) * sc[cu]     + sh[cu],     0.0f);
        tile[nl][cu + 1] = fmaxf(bf2f((ushort_t)(u >> 16))    * sc[cu + 1] + sh[cu + 1], 0.0f);
    }
    __syncthreads();
    float* ob = out + ((size_t)b * H_ + o0) * N2_ + n0;
#pragma unroll
    for (int j = 0; j < 16; ++j) {
        int lin = j * 256 + t;
        int ol = lin >> 6, nl = lin & 63;
        ob[(size_t)ol * N2_ + nl] = tile[nl][ol];
    }
}

// ----------------------------------------------------------------------------
extern "C" void kernel_launch(void* const* d_in, const int* in_sizes, int n_in,
                              void* d_out, int out_size, void* d_ws, size_t ws_size,
                              hipStream_t stream)
{
    (void)in_sizes; (void)n_in; (void)out_size; (void)ws_size;
    const float* points1   = (const float*)d_in[0];
    const float* points2   = (const float*)d_in[1];
    const float* features1 = (const float*)d_in[2];
    const float* features2 = (const float*)d_in[3];
    const float* skipf     = (const float*)d_in[4];
    const float* W1  = (const float*)d_in[5];
    const float* b1  = (const float*)d_in[6];
    const float* g1  = (const float*)d_in[7];
    const float* be1 = (const float*)d_in[8];
    const float* W2  = (const float*)d_in[9];
    const float* b2  = (const float*)d_in[10];
    const float* g2  = (const float*)d_in[11];
    const float* be2 = (const float*)d_in[12];
    float* out = (float*)d_out;

    char* ws = (char*)d_ws;
    float*    s1  = (float*)(ws + 0);
    float*    q1  = (float*)(ws + 1024);
    float*    s2  = (float*)(ws + 2048);
    float*    q2  = (float*)(ws + 3072);
    int*      ind = (int*)(ws + 4096);                 // 393216 B
    float*    wgt = (float*)(ws + 397312);             // 393216 B
    ushort_t* x   = (ushort_t*)(ws + 790528);          // bf16 32768x192 (12.6 MB used)
    ushort_t* y1b = (ushort_t*)(ws + 30150656);        // 16,777,216 B (bf16 raw y1)
    ushort_t* W1b = (ushort_t*)(ws + 63705088);        // 229,376 B
    ushort_t* W2b = (ushort_t*)(ws + 63934464);        // 131,072 B
    ushort_t* f1t = (ushort_t*)(ws + 64065536);        // 4,194,304 B (bf16 8x1024x256)
    ushort_t* y2b = x;                                 // alias: x2 dead after gemm1

    hipMemsetAsync(ws, 0, 4096, stream);               // zero BN stats

    fused_pre<<<dim3(3520), dim3(256), 0, stream>>>(points1, points2, ind, wgt,
                                                    features1, features2, skipf,
                                                    W1, W2, f1t, x, W1b, W2b);

    gemm1_fused<<<dim3(ROWS_ / 64), dim3(512), 0, stream>>>(f1t, ind, wgt, x,
                                                            W1b, b1, y1b, s1, q1);
    gemm2_fused<<<dim3(ROWS_ / 128 * 4), dim3(256), 0, stream>>>(y1b, W2b, b2, s1, q1, g1, be1, y2b, s2, q2);
    bn_out_kernel<<<dim3(2048), dim3(256), 0, stream>>>(y2b, s2, q2, g2, be2, out);
}

// Round 10
// 200.390 us; speedup vs baseline: 1.0196x; 1.0196x over previous
//
#include <hip/hip_runtime.h>
#include <cstdint>
#include <cstddef>

#define B_    8
#define N1_   1024
#define N2_   4096
#define C1_   256
#define C2_   128
#define CS_   64
#define CT_   448
#define H_    256
#define ROWS_ (B_ * N2_)   // 32768
#define XW_   192          // x2 row width: transposed [f2|skip] only

typedef __attribute__((ext_vector_type(8))) short bf16x8;
typedef __attribute__((ext_vector_type(4))) float f32x4;
typedef unsigned short ushort_t;
typedef unsigned int   uint_t;

__device__ __forceinline__ ushort_t f2bf(float f) {
    uint_t u = __float_as_uint(f);
    u = (u + 0x7fffu + ((u >> 16) & 1u)) >> 16;   // RNE
    return (ushort_t)u;
}
__device__ __forceinline__ float bf2f(ushort_t h) {
    return __uint_as_float(((uint_t)h) << 16);
}
// async global->LDS, 16B per lane; LDS dst = wave-uniform base + lane*16
__device__ __forceinline__ void glds16(const void* g, void* l) {
    __builtin_amdgcn_global_load_lds(
        (const __attribute__((address_space(1))) void*)g,
        (__attribute__((address_space(3))) void*)l, 16, 0, 0);
}

// XCD-affine tile decode (used by gemm2 only; neutral perf, kept).
__device__ __forceinline__ void tile_decode(int d, int& m0, int& n0) {
    const int j = d >> 3;
    m0 = ((d & 7) * 32 + (j >> 2)) * 128;
    n0 = (j & 3) * 64;
}

// ---------------------------------------------------------------- fused KNN + prep
// (unchanged — proven)
__global__ __launch_bounds__(256) void fused_pre(
    const float* __restrict__ p1, const float* __restrict__ p2,
    int* __restrict__ ind, float* __restrict__ wout,
    const float* __restrict__ f1, const float* __restrict__ f2,
    const float* __restrict__ fs, const float* __restrict__ W1,
    const float* __restrict__ W2, ushort_t* __restrict__ f1t,
    ushort_t* __restrict__ x, ushort_t* __restrict__ W1b, ushort_t* __restrict__ W2b)
{
#pragma clang fp contract(off)
    __shared__ __align__(16) char smem[32000];
    const int t = threadIdx.x;
    const int bid = blockIdx.x;
    if (bid < 1024) {
        float4*   cand  = (float4*)(smem);
        float*    pvals = (float*)(smem + 16512);
        float*    thr   = (float*)(smem + 19584);
        ushort_t* lists = (ushort_t*)(smem + 19712);
        float*    pdd   = (float*)(smem + 25856);
        int*      pdi   = (int*)(smem + 28928);
        const int b  = bid >> 7;
        const int qb = (bid & 127) * 32;
        const float* pb1 = p1 + (size_t)b * 3 * N1_;
        for (int i = t; i < N1_; i += 256) {
            float X = pb1[i], Y = pb1[N1_ + i], Z = pb1[2 * N1_ + i];
            cand[i] = make_float4(X, Y, Z, (X * X + Y * Y) + Z * Z);
        }
        const int q = t & 31, split = t >> 5;
        const int n = qb + q;
        const float* pb2 = p2 + (size_t)b * 3 * N2_;
        const float ax = pb2[n], ay = pb2[N2_ + n], az = pb2[2 * N2_ + n];
        const float s2a = (ax * ax + ay * ay) + az * az;
        const float m2x = -2.0f * ax, m2y = -2.0f * ay, m2z = -2.0f * az;
        __syncthreads();
        const int ibeg = split * 128, iend = ibeg + 128;
        {
            float a0 = 3e38f, a1 = 3e38f, a2 = 3e38f;
            for (int i = ibeg; i < iend; ++i) {
                float4 c = cand[i];
                float fd = fmaf(c.x, m2x, fmaf(c.y, m2y, fmaf(c.z, m2z, s2a + c.w)));
                float o0 = a0, o1 = a1;
                a0 = fminf(o0, fd);
                a1 = __builtin_amdgcn_fmed3f(fd, o0, o1);
                a2 = __builtin_amdgcn_fmed3f(fd, o1, a2);
            }
            pvals[t * 3 + 0] = a0; pvals[t * 3 + 1] = a1; pvals[t * 3 + 2] = a2;
        }
        __syncthreads();
        if (t < 32) {
            float m0 = 3e38f, m1 = 3e38f, m2v = 3e38f;
#pragma unroll
            for (int g = 0; g < 8; ++g)
#pragma unroll
                for (int r = 0; r < 3; ++r) {
                    float v = pvals[(g * 32 + t) * 3 + r];
                    float o0 = m0, o1 = m1;
                    m0 = fminf(o0, v);
                    m1 = __builtin_amdgcn_fmed3f(v, o0, o1);
                    m2v = __builtin_amdgcn_fmed3f(v, o1, m2v);
                }
            thr[t] = m2v + 2e-3f;
        }
        __syncthreads();
        const float th = thr[q];
        ushort_t* mylist = lists + (q * 8 + split) * 12;
        int cnt = 0;
        for (int i = ibeg; i < iend; ++i) {
            float4 c = cand[i];
            float fd = fmaf(c.x, m2x, fmaf(c.y, m2y, fmaf(c.z, m2z, s2a + c.w)));
            if (fd <= th && cnt < 12) { mylist[cnt] = (ushort_t)i; cnt++; }
        }
        float e0 = 3e38f, e1 = 3e38f, e2 = 3e38f;
        int   j0 = 0, j1 = 0, j2 = 0;
        for (int k = 0; k < cnt; ++k) {
            const int i = mylist[k];
            float4 c = cand[i];
            float dot = (ax * c.x + ay * c.y) + az * c.z;
            float dd  = (s2a + c.w) - 2.0f * dot;
            float d   = sqrtf(fmaxf(dd, 0.0f));
            if (d < e0)      { e2 = e1; j2 = j1; e1 = e0; j1 = j0; e0 = d; j0 = i; }
            else if (d < e1) { e2 = e1; j2 = j1; e1 = d;  j1 = i; }
            else if (d < e2) { e2 = d;  j2 = i; }
        }
        pdd[(split * 32 + q) * 3 + 0] = e0; pdi[(split * 32 + q) * 3 + 0] = j0;
        pdd[(split * 32 + q) * 3 + 1] = e1; pdi[(split * 32 + q) * 3 + 1] = j1;
        pdd[(split * 32 + q) * 3 + 2] = e2; pdi[(split * 32 + q) * 3 + 2] = j2;
        __syncthreads();
        if (t < 32) {
            float f0 = 3e38f, f1v = 3e38f, f2v = 3e38f;
            int   k0 = 0, k1 = 0, k2 = 0;
#pragma unroll
            for (int g = 0; g < 8; ++g)
#pragma unroll
                for (int r = 0; r < 3; ++r) {
                    float d = pdd[(g * 32 + t) * 3 + r];
                    int   i = pdi[(g * 32 + t) * 3 + r];
                    if (d < f0)       { f2v = f1v; k2 = k1; f1v = f0; k1 = k0; f0 = d; k0 = i; }
                    else if (d < f1v) { f2v = f1v; k2 = k1; f1v = d;  k1 = i; }
                    else if (d < f2v) { f2v = d;  k2 = i; }
                }
            float inv0 = 1.0f / (f0 + 1e-10f);
            float inv1 = 1.0f / (f1v + 1e-10f);
            float inv2 = 1.0f / (f2v + 1e-10f);
            float s = (inv0 + inv1) + inv2;
            const size_t row = (size_t)b * N2_ + qb + t;
            wout[row * 3 + 0] = inv0 / s;
            wout[row * 3 + 1] = inv1 / s;
            wout[row * 3 + 2] = inv2 / s;
            ind[row * 3 + 0] = k0;
            ind[row * 3 + 1] = k1;
            ind[row * 3 + 2] = k2;
        }
    } else if (bid < 1536) {
        float (*tile)[65] = (float (*)[65])smem;
        const int bid2 = bid - 1024;
        const int b  = bid2 >> 6;
        const int ct = (bid2 >> 4) & 3;
        const int nt = bid2 & 15;
        const int c0 = ct * 64, n0 = nt * 64;
        const float* src = f1 + ((size_t)b * C1_ + c0) * N1_ + n0;
#pragma unroll
        for (int j = 0; j < 16; ++j) {
            int lin = j * 256 + t;
            int ci = lin >> 6, nj = lin & 63;
            tile[ci][nj] = src[(size_t)ci * N1_ + nj];
        }
        __syncthreads();
        ushort_t* dst = f1t + ((size_t)b * N1_ + n0) * C1_ + c0;
#pragma unroll
        for (int j = 0; j < 8; ++j) {
            int lin = j * 256 + t;
            int ni = lin >> 5, cjp = (lin & 31) * 2;
            uint_t u = (uint_t)f2bf(tile[cjp][ni]) | ((uint_t)f2bf(tile[cjp + 1][ni]) << 16);
            *(uint_t*)&dst[(size_t)ni * C1_ + cjp] = u;
        }
    } else if (bid < 3072) {
        float (*tile)[65] = (float (*)[65])smem;
        const int bid2 = bid - 1536;
        const int b   = bid2 / 192;
        const int rem = bid2 - b * 192;
        const int ct  = rem >> 6;            // 0,1 -> f2 halves, 2 -> skip
        const int nt  = rem & 63;
        const float* src;
        if (ct < 2) src = f2 + ((size_t)b * C2_ + ct * 64) * N2_;
        else        src = fs + (size_t)b * CS_ * N2_;
        const int coff = ct * 64;            // column offset inside x2 (width 192)
        const int n0 = nt * 64;
#pragma unroll
        for (int j = 0; j < 16; ++j) {
            int lin = j * 256 + t;
            int ci = lin >> 6, nj = lin & 63;
            tile[ci][nj] = src[(size_t)ci * N2_ + n0 + nj];
        }
        __syncthreads();
#pragma unroll
        for (int j = 0; j < 8; ++j) {
            int lin = j * 256 + t;
            int ni = lin >> 5, cjp = (lin & 31) * 2;
            uint_t u = (uint_t)f2bf(tile[cjp][ni]) | ((uint_t)f2bf(tile[cjp + 1][ni]) << 16);
            *(uint_t*)&x[((size_t)b * N2_ + n0 + ni) * XW_ + coff + cjp] = u;
        }
    } else {
        const int i = (bid - 3072) * 256 + t;
        if (i < H_ * CT_) W1b[i] = f2bf(W1[i]);
        if (i < H_ * H_)  W2b[i] = f2bf(W2[i]);
    }
}

// ------------------------------- GEMM1, BM=64 x BN=256 @ 512 threads, with the
// gather+interp HOISTED OUT of the K-loop (R9 post-mortem: scattered gather
// loads inside the 2-barrier-per-K-step path were the invariant across all
// failed tile shapes — every wave waited on the block's slowest gather every
// K-step). Phase 1: gather+interp the full 64x256 A-panel into LDS once, 12
// independent uint4 loads/thread (deep MLP, no barriers inside). K-loop is
// then a pure linear-glds GEMM (gemm2's proven structure): k<256 reads the
// resident A-panel; k>=256 stages x2 slices into a small buffer as before.
// LDS: Abig 32K + Asmall 8K + B 32K = 72KB -> 2 blocks/CU. Same XOR-swizzle
// algebra (slot low3 = chunk^(row&7)); per-output K-order & MFMA sequence
// unchanged -> y1b bit-identical.
__global__ __launch_bounds__(512, 4) void gemm1_fused(
    const ushort_t* __restrict__ f1t, const int* __restrict__ ind,
    const float* __restrict__ wgt, const ushort_t* __restrict__ x2,
    const ushort_t* __restrict__ Bw, const float* __restrict__ bias,
    ushort_t* __restrict__ C, float* __restrict__ ssum, float* __restrict__ ssq)
{
    __shared__ __align__(16) ushort_t smem[36864];   // 72 KB
    ushort_t* Abig   = smem;            // 64 rows x 256 (512B rows, swizzled low3)
    ushort_t* Asmall = smem + 16384;    // 64 rows x 64  (k>=256 staging)
    ushort_t* Bs     = smem + 20480;    // 256 rows x 64 (glds, swizzled slots)
    ushort_t* Cs     = smem;            // epilogue reuse: 64 x 264 = 16896 shorts
    const int t = threadIdx.x;
    const int m0 = blockIdx.x * 64;
    const int lane = t & 63;
    const int wv = t >> 6;                             // 0..7
    const int wr = wv & 1;                             // row group (32 rows)
    const int wc = wv >> 1;                            // col group (64 cols)
    const int lm = lane & 15, lq = lane >> 4;
    const int lrow8  = lane >> 3;                      // 0..7
    const int lchunk = (lane & 7) ^ lrow8;             // swizzled source chunk
    const int aswz = lm & 7;                           // read-side row swizzle
    // B staging: 32 rows/wave, 4 glds16/thread/K-step
    const ushort_t* gB = Bw + (size_t)(wv * 32 + lrow8) * CT_ + lchunk * 8;
    ushort_t* lB = Bs + wv * 2048;
    // Asmall glds staging (k0>=256): 8 rows/wave, 1 glds16/thread
    const ushort_t* gA = x2 + (size_t)(m0 + wv * 8 + lrow8) * XW_ + lchunk * 8;
    ushort_t* lA = Asmall + wv * 512;

    // ---- phase 1: gather + interp full 64x256 A-panel into Abig (once).
    // 8 threads/row; thread handles chunks {tc, tc+8, tc+16, tc+24}.
    {
        const int arow = t >> 3;                       // 0..63
        const int tc   = t & 7;                        // chunk low3
        const size_t grow = (size_t)m0 + arow;
        const int bb_ = (int)(grow >> 12);             // row / N2_
        const int* ip = ind + grow * 3;
        const float* wp = wgt + grow * 3;
        const ushort_t* fb = f1t + (size_t)bb_ * N1_ * C1_;
        const ushort_t* ga0 = fb + (size_t)ip[0] * C1_ + tc * 8;
        const ushort_t* ga1 = fb + (size_t)ip[1] * C1_ + tc * 8;
        const ushort_t* ga2 = fb + (size_t)ip[2] * C1_ + tc * 8;
        const float w0 = wp[0], w1 = wp[1], w2 = wp[2];
        const int slot3 = tc ^ (arow & 7);             // swizzled low3 slot
        ushort_t* awr = Abig + arow * 256 + slot3 * 8;
        uint4 va[4], vb[4], vc[4];
#pragma unroll
        for (int g = 0; g < 4; ++g) {                  // issue all 12 loads (MLP)
            va[g] = *(const uint4*)(ga0 + g * 64);
            vb[g] = *(const uint4*)(ga1 + g * 64);
            vc[g] = *(const uint4*)(ga2 + g * 64);
        }
#pragma unroll
        for (int g = 0; g < 4; ++g) {
            const uint_t* pa = (const uint_t*)&va[g];
            const uint_t* pb = (const uint_t*)&vb[g];
            const uint_t* pc = (const uint_t*)&vc[g];
            uint_t o[4];
#pragma unroll
            for (int e = 0; e < 4; ++e) {
                float lo = w0 * bf2f((ushort_t)(pa[e] & 0xffff))
                         + w1 * bf2f((ushort_t)(pb[e] & 0xffff))
                         + w2 * bf2f((ushort_t)(pc[e] & 0xffff));
                float hi = w0 * bf2f((ushort_t)(pa[e] >> 16))
                         + w1 * bf2f((ushort_t)(pb[e] >> 16))
                         + w2 * bf2f((ushort_t)(pc[e] >> 16));
                o[e] = (uint_t)f2bf(lo) | ((uint_t)f2bf(hi) << 16);
            }
            *(uint4*)&awr[g * 64] = *(uint4*)o;
        }
    }

    f32x4 acc[2][4];
#pragma unroll
    for (int i = 0; i < 2; ++i)
#pragma unroll
        for (int j = 0; j < 4; ++j)
            acc[i][j] = (f32x4){0.f, 0.f, 0.f, 0.f};

    // ---- K-steps 0..3: A resident in Abig, stage B only
    for (int k0 = 0; k0 < 256; k0 += 64) {
        __syncthreads();                  // k0=0: phase-1 writes visible; else prev reads done
#pragma unroll
        for (int g = 0; g < 4; ++g)
            glds16(gB + k0 + g * 8 * CT_, lB + g * 512);
        __syncthreads();                  // drains vmcnt -> B in LDS
#pragma unroll
        for (int h = 0; h < 2; ++h) {
            bf16x8 af[2], bfr[4];
#pragma unroll
            for (int i = 0; i < 2; ++i)
                af[i] = *(const bf16x8*)&Abig[(wr * 32 + i * 16 + lm) * 256
                                              + k0 + (((h * 4 + lq) ^ aswz)) * 8];
#pragma unroll
            for (int j = 0; j < 4; ++j)
                bfr[j] = *(const bf16x8*)&Bs[(wc * 64 + j * 16 + lm) * 64
                                             + (((h * 4 + lq) ^ aswz)) * 8];
#pragma unroll
            for (int i = 0; i < 2; ++i)
#pragma unroll
                for (int j = 0; j < 4; ++j)
                    acc[i][j] = __builtin_amdgcn_mfma_f32_16x16x32_bf16(af[i], bfr[j], acc[i][j], 0, 0, 0);
        }
    }
    // ---- K-steps 4..6: stage Asmall (x2) + B
    for (int k0 = 256; k0 < CT_; k0 += 64) {
        __syncthreads();
        glds16(gA + (k0 - 256), lA);
#pragma unroll
        for (int g = 0; g < 4; ++g)
            glds16(gB + k0 + g * 8 * CT_, lB + g * 512);
        __syncthreads();
#pragma unroll
        for (int h = 0; h < 2; ++h) {
            bf16x8 af[2], bfr[4];
#pragma unroll
            for (int i = 0; i < 2; ++i)
                af[i] = *(const bf16x8*)&Asmall[(wr * 32 + i * 16 + lm) * 64
                                                + (((h * 4 + lq) ^ aswz)) * 8];
#pragma unroll
            for (int j = 0; j < 4; ++j)
                bfr[j] = *(const bf16x8*)&Bs[(wc * 64 + j * 16 + lm) * 64
                                             + (((h * 4 + lq) ^ aswz)) * 8];
#pragma unroll
            for (int i = 0; i < 2; ++i)
#pragma unroll
                for (int j = 0; j < 4; ++j)
                    acc[i][j] = __builtin_amdgcn_mfma_f32_16x16x32_bf16(af[i], bfr[j], acc[i][j], 0, 0, 0);
        }
    }

    __syncthreads();
#pragma unroll
    for (int j = 0; j < 4; ++j) {
        const int gn = wc * 64 + j * 16 + lm;          // global col (BN = H)
        const float bb = bias[gn];
        float ps = 0.0f, pq = 0.0f;
#pragma unroll
        for (int i = 0; i < 2; ++i) {
            const int row_l = wr * 32 + i * 16 + lq * 4;
            f32x4 v = acc[i][j];
#pragma unroll
            for (int r = 0; r < 4; ++r) {
                float val = v[r] + bb;
                ps += val;
                pq += val * val;
                float vo = __shfl_xor(val, 1);
                uint_t packed = (lm & 1)
                    ? ((uint_t)f2bf(vo)  | ((uint_t)f2bf(val) << 16))
                    : ((uint_t)f2bf(val) | ((uint_t)f2bf(vo)  << 16));
                if ((lm & 1) == 0)
                    *(uint_t*)&Cs[(row_l + r) * 264 + (gn & ~1)] = packed;
            }
        }
        ps += __shfl_xor(ps, 16); pq += __shfl_xor(pq, 16);
        ps += __shfl_xor(ps, 32); pq += __shfl_xor(pq, 32);
        if (lane < 16) {
            atomicAdd(&ssum[gn], ps);
            atomicAdd(&ssq[gn], pq);
        }
    }
    __syncthreads();
    const int srow = t >> 5;                           // 0..15
    const int scol = (t & 31) * 8;                     // 0..248
#pragma unroll
    for (int rep = 0; rep < 4; ++rep) {
        const int row = srow + rep * 16;
        uint4 v = *(const uint4*)&Cs[row * 264 + scol];
        *(uint4*)(C + (size_t)(m0 + row) * H_ + scol) = v;
    }
}

// ------------------------------- GEMM2: BK=64, BN1+ReLU fused A-staging
// (unchanged — R3-proven)
__global__ __launch_bounds__(256, 4) void gemm2_fused(
    const ushort_t* __restrict__ A, const ushort_t* __restrict__ Bw,
    const float* __restrict__ bias,
    const float* __restrict__ s1, const float* __restrict__ q1,
    const float* __restrict__ g1, const float* __restrict__ be1,
    ushort_t* __restrict__ C, float* __restrict__ ssum, float* __restrict__ ssq)
{
    __shared__ __align__(16) ushort_t smem[15360];   // 30.7 KB
    ushort_t* As0 = smem;                    // 128 x 40 padded (k-half 0)
    ushort_t* As1 = smem + 5120;             // 128 x 40 padded (k-half 1)
    ushort_t* Bs  = smem + 10240;            //  64 x 64 swizzled (glds)
    float*    sc  = (float*)(smem + 14336);  // 256 floats
    float*    sh  = (float*)(smem + 14848);  // 256 floats
    ushort_t* Cs  = smem;                    // epilogue reuse
    const int t = threadIdx.x;
    int m0, n0;
    tile_decode(blockIdx.x, m0, n0);
    const int lane = t & 63;
    const int wv = t >> 6;
    const int wrow = wv & 1, wcol = wv >> 1;
    const int lm = lane & 15, lq = lane >> 4;
    const int lrow8  = lane >> 3;
    const int lchunk = (lane & 7) ^ lrow8;
    const int aswz = lm & 7;
    const int arow = t >> 1, acol = (t & 1) * 32;     // A staging: 32 cols/thread
    {
        const float invN = 1.0f / (float)ROWS_;
        float mu  = s1[t] * invN;
        float var = q1[t] * invN - mu * mu;
        float s   = rsqrtf(var + 1e-3f) * g1[t];
        sc[t] = s;
        sh[t] = be1[t] - mu * s;
    }
    const ushort_t* gB = Bw + (size_t)(n0 + wv * 16 + lrow8) * H_ + lchunk * 8;
    ushort_t* lB = Bs + wv * 1024;
    const ushort_t* gA = A + (size_t)(m0 + arow) * H_ + acol;
    ushort_t* As_t = (t & 1) ? As1 : As0;
    f32x4 acc[4][2];
#pragma unroll
    for (int i = 0; i < 4; ++i)
#pragma unroll
        for (int j = 0; j < 2; ++j)
            acc[i][j] = (f32x4){0.f, 0.f, 0.f, 0.f};

    for (int k0 = 0; k0 < H_; k0 += 64) {
        uint4 av[4];
#pragma unroll
        for (int g = 0; g < 4; ++g)
            av[g] = *(const uint4*)(gA + k0 + g * 8);   // issued before barrier
        __syncthreads();                  // prev reads done; sc/sh visible (1st iter)
#pragma unroll
        for (int g = 0; g < 2; ++g)
            glds16(gB + k0 + g * 8 * H_, lB + g * 512);
#pragma unroll
        for (int g = 0; g < 4; ++g) {
            const uint_t* wsrc = (const uint_t*)&av[g];
            uint_t o[4];
#pragma unroll
            for (int e = 0; e < 4; ++e) {
                const int cb = k0 + acol + g * 8 + 2 * e;
                float lo = __uint_as_float(wsrc[e] << 16);
                float hi = __uint_as_float(wsrc[e] & 0xffff0000u);
                float r0 = fmaxf(fmaf(lo, sc[cb],     sh[cb]),     0.0f);
                float r1 = fmaxf(fmaf(hi, sc[cb + 1], sh[cb + 1]), 0.0f);
                o[e] = (uint_t)f2bf(r0) | ((uint_t)f2bf(r1) << 16);
            }
            *(uint4*)&As_t[arow * 40 + g * 8] = *(uint4*)o;
        }
        __syncthreads();                  // drains vmcnt (B) + lgkm (As)
#pragma unroll
        for (int h = 0; h < 2; ++h) {
            const ushort_t* Ah = h ? As1 : As0;
            bf16x8 af[4], bfr[2];
#pragma unroll
            for (int i = 0; i < 4; ++i)
                af[i] = *(const bf16x8*)&Ah[(wrow * 64 + i * 16 + lm) * 40 + lq * 8];
#pragma unroll
            for (int j = 0; j < 2; ++j)
                bfr[j] = *(const bf16x8*)&Bs[(wcol * 32 + j * 16 + lm) * 64
                                             + (((h * 4 + lq) ^ aswz)) * 8];
#pragma unroll
            for (int i = 0; i < 4; ++i)
#pragma unroll
                for (int j = 0; j < 2; ++j)
                    acc[i][j] = __builtin_amdgcn_mfma_f32_16x16x32_bf16(af[i], bfr[j], acc[i][j], 0, 0, 0);
        }
    }
    __syncthreads();
#pragma unroll
    for (int j = 0; j < 2; ++j) {
        const int gn_l = wcol * 32 + j * 16 + lm;
        const int gn   = n0 + gn_l;
        const float bb = bias[gn];
        float ps = 0.0f, pq = 0.0f;
#pragma unroll
        for (int i = 0; i < 4; ++i) {
            const int row_l = wrow * 64 + i * 16 + lq * 4;
            f32x4 v = acc[i][j];
#pragma unroll
            for (int r = 0; r < 4; ++r) {
                float val = v[r] + bb;
                ps += val;
                pq += val * val;
                float vo = __shfl_xor(val, 1);
                uint_t packed = (lm & 1)
                    ? ((uint_t)f2bf(vo)  | ((uint_t)f2bf(val) << 16))
                    : ((uint_t)f2bf(val) | ((uint_t)f2bf(vo)  << 16));
                if ((lm & 1) == 0)
                    *(uint_t*)&Cs[(row_l + r) * 72 + (gn_l & ~1)] = packed;
            }
        }
        ps += __shfl_xor(ps, 16); pq += __shfl_xor(pq, 16);
        ps += __shfl_xor(ps, 32); pq += __shfl_xor(pq, 32);
        if (lane < 16) {
            atomicAdd(&ssum[gn], ps);
            atomicAdd(&ssq[gn], pq);
        }
    }
    __syncthreads();
    const int srow = t >> 3;
    const int scol = (t & 7) * 8;
#pragma unroll
    for (int rep = 0; rep < 4; ++rep) {
        const int row = srow + rep * 32;
        uint4 v = *(const uint4*)&Cs[row * 72 + scol];
        *(uint4*)(C + (size_t)(m0 + row) * H_ + n0 + scol) = v;
    }
}

// ------------------------------- BN2 + ReLU + transpose (unchanged)
__global__ __launch_bounds__(256) void bn_out_kernel(
    const ushort_t* __restrict__ y, const float* __restrict__ ssum, const float* __restrict__ ssq,
    const float* __restrict__ g, const float* __restrict__ beta, float* __restrict__ out)
{
    __shared__ float tile[64][65];
    __shared__ float sc[64], sh[64];
    const float invN = 1.0f / (float)ROWS_;
    const int bid = blockIdx.x;
    const int b  = bid >> 8;
    const int nt = (bid >> 2) & 63;
    const int ot = bid & 3;
    const int t = threadIdx.x;
    if (t < 64) {
        int c = ot * 64 + t;
        float mu  = ssum[c] * invN;
        float var = ssq[c] * invN - mu * mu;
        float s   = rsqrtf(var + 1e-3f) * g[c];
        sc[t] = s;
        sh[t] = beta[c] - mu * s;
    }
    __syncthreads();
    const int n0 = nt * 64, o0 = ot * 64;
    const ushort_t* yb = y + ((size_t)b * N2_ + n0) * H_ + o0;
#pragma unroll
    for (int j = 0; j < 8; ++j) {
        int lin = j * 256 + t;
        int nl = lin >> 5, cu = (lin & 31) * 2;
        uint_t u = *(const uint_t*)&yb[(size_t)nl * H_ + cu];
        tile[nl][cu]     = fmaxf(bf2f((ushort_t)(u & 0xffff)) * sc[cu]     + sh[cu],     0.0f);
        tile[nl][cu + 1] = fmaxf(bf2f((ushort_t)(u >> 16))    * sc[cu + 1] + sh[cu + 1], 0.0f);
    }
    __syncthreads();
    float* ob = out + ((size_t)b * H_ + o0) * N2_ + n0;
#pragma unroll
    for (int j = 0; j < 16; ++j) {
        int lin = j * 256 + t;
        int ol = lin >> 6, nl = lin & 63;
        ob[(size_t)ol * N2_ + nl] = tile[nl][ol];
    }
}

// ----------------------------------------------------------------------------
extern "C" void kernel_launch(void* const* d_in, const int* in_sizes, int n_in,
                              void* d_out, int out_size, void* d_ws, size_t ws_size,
                              hipStream_t stream)
{
    (void)in_sizes; (void)n_in; (void)out_size; (void)ws_size;
    const float* points1   = (const float*)d_in[0];
    const float* points2   = (const float*)d_in[1];
    const float* features1 = (const float*)d_in[2];
    const float* features2 = (const float*)d_in[3];
    const float* skipf     = (const float*)d_in[4];
    const float* W1  = (const float*)d_in[5];
    const float* b1  = (const float*)d_in[6];
    const float* g1  = (const float*)d_in[7];
    const float* be1 = (const float*)d_in[8];
    const float* W2  = (const float*)d_in[9];
    const float* b2  = (const float*)d_in[10];
    const float* g2  = (const float*)d_in[11];
    const float* be2 = (const float*)d_in[12];
    float* out = (float*)d_out;

    char* ws = (char*)d_ws;
    float*    s1  = (float*)(ws + 0);
    float*    q1  = (float*)(ws + 1024);
    float*    s2  = (float*)(ws + 2048);
    float*    q2  = (float*)(ws + 3072);
    int*      ind = (int*)(ws + 4096);                 // 393216 B
    float*    wgt = (float*)(ws + 397312);             // 393216 B
    ushort_t* x   = (ushort_t*)(ws + 790528);          // bf16 32768x192 (12.6 MB used)
    ushort_t* y1b = (ushort_t*)(ws + 30150656);        // 16,777,216 B (bf16 raw y1)
    ushort_t* W1b = (ushort_t*)(ws + 63705088);        // 229,376 B
    ushort_t* W2b = (ushort_t*)(ws + 63934464);        // 131,072 B
    ushort_t* f1t = (ushort_t*)(ws + 64065536);        // 4,194,304 B (bf16 8x1024x256)
    ushort_t* y2b = x;                                 // alias: x2 dead after gemm1

    hipMemsetAsync(ws, 0, 4096, stream);               // zero BN stats

    fused_pre<<<dim3(3520), dim3(256), 0, stream>>>(points1, points2, ind, wgt,
                                                    features1, features2, skipf,
                                                    W1, W2, f1t, x, W1b, W2b);

    gemm1_fused<<<dim3(ROWS_ / 64), dim3(512), 0, stream>>>(f1t, ind, wgt, x,
                                                            W1b, b1, y1b, s1, q1);
    gemm2_fused<<<dim3(ROWS_ / 128 * 4), dim3(256), 0, stream>>>(y1b, W2b, b2, s1, q1, g1, be1, y2b, s2, q2);
    bn_out_kernel<<<dim3(2048), dim3(256), 0, stream>>>(y2b, s2, q2, g2, be2, out);
}

// Round 11
// 188.526 us; speedup vs baseline: 1.0838x; 1.0629x over previous
//
#include <hip/hip_runtime.h>
#include <cstdint>
#include <cstddef>

#define B_    8
#define N1_   1024
#define N2_   4096
#define C1_   256
#define C2_   128
#define CS_   64
#define CT_   448
#define H_    256
#define ROWS_ (B_ * N2_)   // 32768
#define XW_   192          // x2 row width: transposed [f2|skip] only

typedef __attribute__((ext_vector_type(8))) short bf16x8;
typedef __attribute__((ext_vector_type(4))) float f32x4;
typedef unsigned short ushort_t;
typedef unsigned int   uint_t;

__device__ __forceinline__ ushort_t f2bf(float f) {
    uint_t u = __float_as_uint(f);
    u = (u + 0x7fffu + ((u >> 16) & 1u)) >> 16;   // RNE
    return (ushort_t)u;
}
__device__ __forceinline__ float bf2f(ushort_t h) {
    return __uint_as_float(((uint_t)h) << 16);
}
// async global->LDS, 16B per lane; LDS dst = wave-uniform base + lane*16
__device__ __forceinline__ void glds16(const void* g, void* l) {
    __builtin_amdgcn_global_load_lds(
        (const __attribute__((address_space(1))) void*)g,
        (__attribute__((address_space(3))) void*)l, 16, 0, 0);
}

// XCD-affine tile decode (used by gemm2 only; neutral perf, kept).
__device__ __forceinline__ void tile_decode(int d, int& m0, int& n0) {
    const int j = d >> 3;
    m0 = ((d & 7) * 32 + (j >> 2)) * 128;
    n0 = (j & 3) * 64;
}

// ---------------------------------------------------------------- fused KNN + prep
// (unchanged — proven)
__global__ __launch_bounds__(256) void fused_pre(
    const float* __restrict__ p1, const float* __restrict__ p2,
    int* __restrict__ ind, float* __restrict__ wout,
    const float* __restrict__ f1, const float* __restrict__ f2,
    const float* __restrict__ fs, const float* __restrict__ W1,
    const float* __restrict__ W2, ushort_t* __restrict__ f1t,
    ushort_t* __restrict__ x, ushort_t* __restrict__ W1b, ushort_t* __restrict__ W2b)
{
#pragma clang fp contract(off)
    __shared__ __align__(16) char smem[32000];
    const int t = threadIdx.x;
    const int bid = blockIdx.x;
    if (bid < 1024) {
        float4*   cand  = (float4*)(smem);
        float*    pvals = (float*)(smem + 16512);
        float*    thr   = (float*)(smem + 19584);
        ushort_t* lists = (ushort_t*)(smem + 19712);
        float*    pdd   = (float*)(smem + 25856);
        int*      pdi   = (int*)(smem + 28928);
        const int b  = bid >> 7;
        const int qb = (bid & 127) * 32;
        const float* pb1 = p1 + (size_t)b * 3 * N1_;
        for (int i = t; i < N1_; i += 256) {
            float X = pb1[i], Y = pb1[N1_ + i], Z = pb1[2 * N1_ + i];
            cand[i] = make_float4(X, Y, Z, (X * X + Y * Y) + Z * Z);
        }
        const int q = t & 31, split = t >> 5;
        const int n = qb + q;
        const float* pb2 = p2 + (size_t)b * 3 * N2_;
        const float ax = pb2[n], ay = pb2[N2_ + n], az = pb2[2 * N2_ + n];
        const float s2a = (ax * ax + ay * ay) + az * az;
        const float m2x = -2.0f * ax, m2y = -2.0f * ay, m2z = -2.0f * az;
        __syncthreads();
        const int ibeg = split * 128, iend = ibeg + 128;
        {
            float a0 = 3e38f, a1 = 3e38f, a2 = 3e38f;
            for (int i = ibeg; i < iend; ++i) {
                float4 c = cand[i];
                float fd = fmaf(c.x, m2x, fmaf(c.y, m2y, fmaf(c.z, m2z, s2a + c.w)));
                float o0 = a0, o1 = a1;
                a0 = fminf(o0, fd);
                a1 = __builtin_amdgcn_fmed3f(fd, o0, o1);
                a2 = __builtin_amdgcn_fmed3f(fd, o1, a2);
            }
            pvals[t * 3 + 0] = a0; pvals[t * 3 + 1] = a1; pvals[t * 3 + 2] = a2;
        }
        __syncthreads();
        if (t < 32) {
            float m0 = 3e38f, m1 = 3e38f, m2v = 3e38f;
#pragma unroll
            for (int g = 0; g < 8; ++g)
#pragma unroll
                for (int r = 0; r < 3; ++r) {
                    float v = pvals[(g * 32 + t) * 3 + r];
                    float o0 = m0, o1 = m1;
                    m0 = fminf(o0, v);
                    m1 = __builtin_amdgcn_fmed3f(v, o0, o1);
                    m2v = __builtin_amdgcn_fmed3f(v, o1, m2v);
                }
            thr[t] = m2v + 2e-3f;
        }
        __syncthreads();
        const float th = thr[q];
        ushort_t* mylist = lists + (q * 8 + split) * 12;
        int cnt = 0;
        for (int i = ibeg; i < iend; ++i) {
            float4 c = cand[i];
            float fd = fmaf(c.x, m2x, fmaf(c.y, m2y, fmaf(c.z, m2z, s2a + c.w)));
            if (fd <= th && cnt < 12) { mylist[cnt] = (ushort_t)i; cnt++; }
        }
        float e0 = 3e38f, e1 = 3e38f, e2 = 3e38f;
        int   j0 = 0, j1 = 0, j2 = 0;
        for (int k = 0; k < cnt; ++k) {
            const int i = mylist[k];
            float4 c = cand[i];
            float dot = (ax * c.x + ay * c.y) + az * c.z;
            float dd  = (s2a + c.w) - 2.0f * dot;
            float d   = sqrtf(fmaxf(dd, 0.0f));
            if (d < e0)      { e2 = e1; j2 = j1; e1 = e0; j1 = j0; e0 = d; j0 = i; }
            else if (d < e1) { e2 = e1; j2 = j1; e1 = d;  j1 = i; }
            else if (d < e2) { e2 = d;  j2 = i; }
        }
        pdd[(split * 32 + q) * 3 + 0] = e0; pdi[(split * 32 + q) * 3 + 0] = j0;
        pdd[(split * 32 + q) * 3 + 1] = e1; pdi[(split * 32 + q) * 3 + 1] = j1;
        pdd[(split * 32 + q) * 3 + 2] = e2; pdi[(split * 32 + q) * 3 + 2] = j2;
        __syncthreads();
        if (t < 32) {
            float f0 = 3e38f, f1v = 3e38f, f2v = 3e38f;
            int   k0 = 0, k1 = 0, k2 = 0;
#pragma unroll
            for (int g = 0; g < 8; ++g)
#pragma unroll
                for (int r = 0; r < 3; ++r) {
                    float d = pdd[(g * 32 + t) * 3 + r];
                    int   i = pdi[(g * 32 + t) * 3 + r];
                    if (d < f0)       { f2v = f1v; k2 = k1; f1v = f0; k1 = k0; f0 = d; k0 = i; }
                    else if (d < f1v) { f2v = f1v; k2 = k1; f1v = d;  k1 = i; }
                    else if (d < f2v) { f2v = d;  k2 = i; }
                }
            float inv0 = 1.0f / (f0 + 1e-10f);
            float inv1 = 1.0f / (f1v + 1e-10f);
            float inv2 = 1.0f / (f2v + 1e-10f);
            float s = (inv0 + inv1) + inv2;
            const size_t row = (size_t)b * N2_ + qb + t;
            wout[row * 3 + 0] = inv0 / s;
            wout[row * 3 + 1] = inv1 / s;
            wout[row * 3 + 2] = inv2 / s;
            ind[row * 3 + 0] = k0;
            ind[row * 3 + 1] = k1;
            ind[row * 3 + 2] = k2;
        }
    } else if (bid < 1536) {
        float (*tile)[65] = (float (*)[65])smem;
        const int bid2 = bid - 1024;
        const int b  = bid2 >> 6;
        const int ct = (bid2 >> 4) & 3;
        const int nt = bid2 & 15;
        const int c0 = ct * 64, n0 = nt * 64;
        const float* src = f1 + ((size_t)b * C1_ + c0) * N1_ + n0;
#pragma unroll
        for (int j = 0; j < 16; ++j) {
            int lin = j * 256 + t;
            int ci = lin >> 6, nj = lin & 63;
            tile[ci][nj] = src[(size_t)ci * N1_ + nj];
        }
        __syncthreads();
        ushort_t* dst = f1t + ((size_t)b * N1_ + n0) * C1_ + c0;
#pragma unroll
        for (int j = 0; j < 8; ++j) {
            int lin = j * 256 + t;
            int ni = lin >> 5, cjp = (lin & 31) * 2;
            uint_t u = (uint_t)f2bf(tile[cjp][ni]) | ((uint_t)f2bf(tile[cjp + 1][ni]) << 16);
            *(uint_t*)&dst[(size_t)ni * C1_ + cjp] = u;
        }
    } else if (bid < 3072) {
        float (*tile)[65] = (float (*)[65])smem;
        const int bid2 = bid - 1536;
        const int b   = bid2 / 192;
        const int rem = bid2 - b * 192;
        const int ct  = rem >> 6;            // 0,1 -> f2 halves, 2 -> skip
        const int nt  = rem & 63;
        const float* src;
        if (ct < 2) src = f2 + ((size_t)b * C2_ + ct * 64) * N2_;
        else        src = fs + (size_t)b * CS_ * N2_;
        const int coff = ct * 64;            // column offset inside x2 (width 192)
        const int n0 = nt * 64;
#pragma unroll
        for (int j = 0; j < 16; ++j) {
            int lin = j * 256 + t;
            int ci = lin >> 6, nj = lin & 63;
            tile[ci][nj] = src[(size_t)ci * N2_ + n0 + nj];
        }
        __syncthreads();
#pragma unroll
        for (int j = 0; j < 8; ++j) {
            int lin = j * 256 + t;
            int ni = lin >> 5, cjp = (lin & 31) * 2;
            uint_t u = (uint_t)f2bf(tile[cjp][ni]) | ((uint_t)f2bf(tile[cjp + 1][ni]) << 16);
            *(uint_t*)&x[((size_t)b * N2_ + n0 + ni) * XW_ + coff + cjp] = u;
        }
    } else {
        const int i = (bid - 3072) * 256 + t;
        if (i < H_ * CT_) W1b[i] = f2bf(W1[i]);
        if (i < H_ * H_)  W2b[i] = f2bf(W2[i]);
    }
}

// ------------------------------- GEMM1, re-tiled BM=64 x BN=256 (full H per
// block): gather+interp done ONCE per row. 512 blocks, 4 waves; wave wv owns
// cols [wv*64, wv*64+64). Single-buffer 2-barrier loop. A: 64x64 interp/glds
// staged, XOR-swizzled slots; B: 256x64 glds, same swizzle. Best-measured
// session configuration (R7: 190.17 us total). Session post-mortem: 6 gemm1
// structural variants (dbuf, 32x256, 64x256@512t, hoisted-panel) all landed
// 38-58 us with MfmaUtil 5-6% and nothing saturated -> gather long-tail L2
// latency is the structural floor; reverting to best-known.
__global__ __launch_bounds__(256, 4) void gemm1_fused(
    const ushort_t* __restrict__ f1t, const int* __restrict__ ind,
    const float* __restrict__ wgt, const ushort_t* __restrict__ x2,
    const ushort_t* __restrict__ Bw, const float* __restrict__ bias,
    ushort_t* __restrict__ C, float* __restrict__ ssum, float* __restrict__ ssq)
{
    __shared__ __align__(16) ushort_t smem[20480];   // A 8KB + B 32KB = 40KB
    ushort_t* As = smem;            //  64 rows x 64 (128B rows, swizzled slots)
    ushort_t* Bs = smem + 4096;     // 256 rows x 64 (glds, swizzled slots)
    ushort_t* Cs = smem;            // epilogue reuse: 64 x 264 = 16896 shorts
    const int t = threadIdx.x;
    const int m0 = blockIdx.x * 64;
    const int lane = t & 63;
    const int wv = t >> 6;                             // n-group 0..3
    const int lm = lane & 15, lq = lane >> 4;
    const int lrow8  = lane >> 3;                      // 0..7
    const int lchunk = (lane & 7) ^ lrow8;             // swizzled source chunk
    const int aswz = lm & 7;                           // read-side row swizzle
    // B staging: 64 rows/wave, 8 glds16/thread/K-step
    const ushort_t* gB = Bw + (size_t)(wv * 64 + lrow8) * CT_ + lchunk * 8;
    ushort_t* lB = Bs + wv * 4096;
    // A glds staging (k0>=256): 16 rows/wave from x2 (stride 192, 16B-aligned)
    const ushort_t* gA = x2 + (size_t)(m0 + wv * 16 + lrow8) * XW_ + lchunk * 8;
    ushort_t* lA = As + wv * 1024;
    // A interp staging (k0<256): 4 threads/row, 2 chunks (16 cols) each
    const int arow = t >> 2;                           // 0..63
    const int ac0  = (t & 3) * 2;                      // chunk base 0,2,4,6
    const size_t grow = (size_t)m0 + arow;
    const int bb_ = (int)(grow >> 12);                 // row / N2_
    const int* ip = ind + grow * 3;
    const float* wp = wgt + grow * 3;
    const ushort_t* fb = f1t + (size_t)bb_ * N1_ * C1_;
    const ushort_t* ga0 = fb + (size_t)ip[0] * C1_ + ac0 * 8;
    const ushort_t* ga1 = fb + (size_t)ip[1] * C1_ + ac0 * 8;
    const ushort_t* ga2 = fb + (size_t)ip[2] * C1_ + ac0 * 8;
    const float w0 = wp[0], w1 = wp[1], w2 = wp[2];
    ushort_t* awr = As + arow * 64;
    const int arsw = arow & 7;
    f32x4 acc[4][4];
#pragma unroll
    for (int i = 0; i < 4; ++i)
#pragma unroll
        for (int j = 0; j < 4; ++j)
            acc[i][j] = (f32x4){0.f, 0.f, 0.f, 0.f};

    for (int k0 = 0; k0 < CT_; k0 += 64) {
        __syncthreads();                  // previous iter's LDS reads complete
        if (k0 < 256) {
#pragma unroll
            for (int g = 0; g < 2; ++g) {
                uint4 va = *(const uint4*)(ga0 + k0 + g * 8);
                uint4 vb = *(const uint4*)(ga1 + k0 + g * 8);
                uint4 vc = *(const uint4*)(ga2 + k0 + g * 8);
                const uint_t* pa = (const uint_t*)&va;
                const uint_t* pb = (const uint_t*)&vb;
                const uint_t* pc = (const uint_t*)&vc;
                uint_t o[4];
#pragma unroll
                for (int e = 0; e < 4; ++e) {
                    float lo = w0 * bf2f((ushort_t)(pa[e] & 0xffff))
                             + w1 * bf2f((ushort_t)(pb[e] & 0xffff))
                             + w2 * bf2f((ushort_t)(pc[e] & 0xffff));
                    float hi = w0 * bf2f((ushort_t)(pa[e] >> 16))
                             + w1 * bf2f((ushort_t)(pb[e] >> 16))
                             + w2 * bf2f((ushort_t)(pc[e] >> 16));
                    o[e] = (uint_t)f2bf(lo) | ((uint_t)f2bf(hi) << 16);
                }
                *(uint4*)&awr[((ac0 + g) ^ arsw) * 8] = *(uint4*)o;
            }
        } else {
#pragma unroll
            for (int g = 0; g < 2; ++g)
                glds16(gA + (k0 - 256) + g * 8 * XW_, lA + g * 512);
        }
#pragma unroll
        for (int g = 0; g < 8; ++g)
            glds16(gB + k0 + g * 8 * CT_, lB + g * 512);
        __syncthreads();                  // drains vmcnt + lgkm -> tiles in LDS
#pragma unroll
        for (int h = 0; h < 2; ++h) {
            bf16x8 af[4], bfr[4];
#pragma unroll
            for (int i = 0; i < 4; ++i)
                af[i] = *(const bf16x8*)&As[(i * 16 + lm) * 64
                                            + (((h * 4 + lq) ^ aswz)) * 8];
#pragma unroll
            for (int j = 0; j < 4; ++j)
                bfr[j] = *(const bf16x8*)&Bs[(wv * 64 + j * 16 + lm) * 64
                                             + (((h * 4 + lq) ^ aswz)) * 8];
#pragma unroll
            for (int i = 0; i < 4; ++i)
#pragma unroll
                for (int j = 0; j < 4; ++j)
                    acc[i][j] = __builtin_amdgcn_mfma_f32_16x16x32_bf16(af[i], bfr[j], acc[i][j], 0, 0, 0);
        }
    }
    __syncthreads();
#pragma unroll
    for (int j = 0; j < 4; ++j) {
        const int gn = wv * 64 + j * 16 + lm;          // global col (BN = H)
        const float bb = bias[gn];
        float ps = 0.0f, pq = 0.0f;
#pragma unroll
        for (int i = 0; i < 4; ++i) {
            const int row_l = i * 16 + lq * 4;
            f32x4 v = acc[i][j];
#pragma unroll
            for (int r = 0; r < 4; ++r) {
                float val = v[r] + bb;
                ps += val;
                pq += val * val;
                float vo = __shfl_xor(val, 1);
                uint_t packed = (lm & 1)
                    ? ((uint_t)f2bf(vo)  | ((uint_t)f2bf(val) << 16))
                    : ((uint_t)f2bf(val) | ((uint_t)f2bf(vo)  << 16));
                if ((lm & 1) == 0)
                    *(uint_t*)&Cs[(row_l + r) * 264 + (gn & ~1)] = packed;
            }
        }
        ps += __shfl_xor(ps, 16); pq += __shfl_xor(pq, 16);
        ps += __shfl_xor(ps, 32); pq += __shfl_xor(pq, 32);
        if (lane < 16) {
            atomicAdd(&ssum[gn], ps);
            atomicAdd(&ssq[gn], pq);
        }
    }
    __syncthreads();
    const int srow = t >> 5;                           // 0..7
    const int scol = (t & 31) * 8;                     // 0..248
#pragma unroll
    for (int rep = 0; rep < 8; ++rep) {
        const int row = srow + rep * 8;
        uint4 v = *(const uint4*)&Cs[row * 264 + scol];
        *(uint4*)(C + (size_t)(m0 + row) * H_ + scol) = v;
    }
}

// ------------------------------- GEMM2: BK=64, BN1+ReLU fused A-staging
// (unchanged — R3-proven)
__global__ __launch_bounds__(256, 4) void gemm2_fused(
    const ushort_t* __restrict__ A, const ushort_t* __restrict__ Bw,
    const float* __restrict__ bias,
    const float* __restrict__ s1, const float* __restrict__ q1,
    const float* __restrict__ g1, const float* __restrict__ be1,
    ushort_t* __restrict__ C, float* __restrict__ ssum, float* __restrict__ ssq)
{
    __shared__ __align__(16) ushort_t smem[15360];   // 30.7 KB
    ushort_t* As0 = smem;                    // 128 x 40 padded (k-half 0)
    ushort_t* As1 = smem + 5120;             // 128 x 40 padded (k-half 1)
    ushort_t* Bs  = smem + 10240;            //  64 x 64 swizzled (glds)
    float*    sc  = (float*)(smem + 14336);  // 256 floats
    float*    sh  = (float*)(smem + 14848);  // 256 floats
    ushort_t* Cs  = smem;                    // epilogue reuse
    const int t = threadIdx.x;
    int m0, n0;
    tile_decode(blockIdx.x, m0, n0);
    const int lane = t & 63;
    const int wv = t >> 6;
    const int wrow = wv & 1, wcol = wv >> 1;
    const int lm = lane & 15, lq = lane >> 4;
    const int lrow8  = lane >> 3;
    const int lchunk = (lane & 7) ^ lrow8;
    const int aswz = lm & 7;
    const int arow = t >> 1, acol = (t & 1) * 32;     // A staging: 32 cols/thread
    {
        const float invN = 1.0f / (float)ROWS_;
        float mu  = s1[t] * invN;
        float var = q1[t] * invN - mu * mu;
        float s   = rsqrtf(var + 1e-3f) * g1[t];
        sc[t] = s;
        sh[t] = be1[t] - mu * s;
    }
    const ushort_t* gB = Bw + (size_t)(n0 + wv * 16 + lrow8) * H_ + lchunk * 8;
    ushort_t* lB = Bs + wv * 1024;
    const ushort_t* gA = A + (size_t)(m0 + arow) * H_ + acol;
    ushort_t* As_t = (t & 1) ? As1 : As0;
    f32x4 acc[4][2];
#pragma unroll
    for (int i = 0; i < 4; ++i)
#pragma unroll
        for (int j = 0; j < 2; ++j)
            acc[i][j] = (f32x4){0.f, 0.f, 0.f, 0.f};

    for (int k0 = 0; k0 < H_; k0 += 64) {
        uint4 av[4];
#pragma unroll
        for (int g = 0; g < 4; ++g)
            av[g] = *(const uint4*)(gA + k0 + g * 8);   // issued before barrier
        __syncthreads();                  // prev reads done; sc/sh visible (1st iter)
#pragma unroll
        for (int g = 0; g < 2; ++g)
            glds16(gB + k0 + g * 8 * H_, lB + g * 512);
#pragma unroll
        for (int g = 0; g < 4; ++g) {
            const uint_t* wsrc = (const uint_t*)&av[g];
            uint_t o[4];
#pragma unroll
            for (int e = 0; e < 4; ++e) {
                const int cb = k0 + acol + g * 8 + 2 * e;
                float lo = __uint_as_float(wsrc[e] << 16);
                float hi = __uint_as_float(wsrc[e] & 0xffff0000u);
                float r0 = fmaxf(fmaf(lo, sc[cb],     sh[cb]),     0.0f);
                float r1 = fmaxf(fmaf(hi, sc[cb + 1], sh[cb + 1]), 0.0f);
                o[e] = (uint_t)f2bf(r0) | ((uint_t)f2bf(r1) << 16);
            }
            *(uint4*)&As_t[arow * 40 + g * 8] = *(uint4*)o;
        }
        __syncthreads();                  // drains vmcnt (B) + lgkm (As)
#pragma unroll
        for (int h = 0; h < 2; ++h) {
            const ushort_t* Ah = h ? As1 : As0;
            bf16x8 af[4], bfr[2];
#pragma unroll
            for (int i = 0; i < 4; ++i)
                af[i] = *(const bf16x8*)&Ah[(wrow * 64 + i * 16 + lm) * 40 + lq * 8];
#pragma unroll
            for (int j = 0; j < 2; ++j)
                bfr[j] = *(const bf16x8*)&Bs[(wcol * 32 + j * 16 + lm) * 64
                                             + (((h * 4 + lq) ^ aswz)) * 8];
#pragma unroll
            for (int i = 0; i < 4; ++i)
#pragma unroll
                for (int j = 0; j < 2; ++j)
                    acc[i][j] = __builtin_amdgcn_mfma_f32_16x16x32_bf16(af[i], bfr[j], acc[i][j], 0, 0, 0);
        }
    }
    __syncthreads();
#pragma unroll
    for (int j = 0; j < 2; ++j) {
        const int gn_l = wcol * 32 + j * 16 + lm;
        const int gn   = n0 + gn_l;
        const float bb = bias[gn];
        float ps = 0.0f, pq = 0.0f;
#pragma unroll
        for (int i = 0; i < 4; ++i) {
            const int row_l = wrow * 64 + i * 16 + lq * 4;
            f32x4 v = acc[i][j];
#pragma unroll
            for (int r = 0; r < 4; ++r) {
                float val = v[r] + bb;
                ps += val;
                pq += val * val;
                float vo = __shfl_xor(val, 1);
                uint_t packed = (lm & 1)
                    ? ((uint_t)f2bf(vo)  | ((uint_t)f2bf(val) << 16))
                    : ((uint_t)f2bf(val) | ((uint_t)f2bf(vo)  << 16));
                if ((lm & 1) == 0)
                    *(uint_t*)&Cs[(row_l + r) * 72 + (gn_l & ~1)] = packed;
            }
        }
        ps += __shfl_xor(ps, 16); pq += __shfl_xor(pq, 16);
        ps += __shfl_xor(ps, 32); pq += __shfl_xor(pq, 32);
        if (lane < 16) {
            atomicAdd(&ssum[gn], ps);
            atomicAdd(&ssq[gn], pq);
        }
    }
    __syncthreads();
    const int srow = t >> 3;
    const int scol = (t & 7) * 8;
#pragma unroll
    for (int rep = 0; rep < 4; ++rep) {
        const int row = srow + rep * 32;
        uint4 v = *(const uint4*)&Cs[row * 72 + scol];
        *(uint4*)(C + (size_t)(m0 + row) * H_ + n0 + scol) = v;
    }
}

// ------------------------------- BN2 + ReLU + transpose (unchanged)
__global__ __launch_bounds__(256) void bn_out_kernel(
    const ushort_t* __restrict__ y, const float* __restrict__ ssum, const float* __restrict__ ssq,
    const float* __restrict__ g, const float* __restrict__ beta, float* __restrict__ out)
{
    __shared__ float tile[64][65];
    __shared__ float sc[64], sh[64];
    const float invN = 1.0f / (float)ROWS_;
    const int bid = blockIdx.x;
    const int b  = bid >> 8;
    const int nt = (bid >> 2) & 63;
    const int ot = bid & 3;
    const int t = threadIdx.x;
    if (t < 64) {
        int c = ot * 64 + t;
        float mu  = ssum[c] * invN;
        float var = ssq[c] * invN - mu * mu;
        float s   = rsqrtf(var + 1e-3f) * g[c];
        sc[t] = s;
        sh[t] = beta[c] - mu * s;
    }
    __syncthreads();
    const int n0 = nt * 64, o0 = ot * 64;
    const ushort_t* yb = y + ((size_t)b * N2_ + n0) * H_ + o0;
#pragma unroll
    for (int j = 0; j < 8; ++j) {
        int lin = j * 256 + t;
        int nl = lin >> 5, cu = (lin & 31) * 2;
        uint_t u = *(const uint_t*)&yb[(size_t)nl * H_ + cu];
        tile[nl][cu]     = fmaxf(bf2f((ushort_t)(u & 0xffff)) * sc[cu]     + sh[cu],     0.0f);
        tile[nl][cu + 1] = fmaxf(bf2f((ushort_t)(u >> 16))    * sc[cu + 1] + sh[cu + 1], 0.0f);
    }
    __syncthreads();
    float* ob = out + ((size_t)b * H_ + o0) * N2_ + n0;
#pragma unroll
    for (int j = 0; j < 16; ++j) {
        int lin = j * 256 + t;
        int ol = lin >> 6, nl = lin & 63;
        ob[(size_t)ol * N2_ + nl] = tile[nl][ol];
    }
}

// ----------------------------------------------------------------------------
extern "C" void kernel_launch(void* const* d_in, const int* in_sizes, int n_in,
                              void* d_out, int out_size, void* d_ws, size_t ws_size,
                              hipStream_t stream)
{
    (void)in_sizes; (void)n_in; (void)out_size; (void)ws_size;
    const float* points1   = (const float*)d_in[0];
    const float* points2   = (const float*)d_in[1];
    const float* features1 = (const float*)d_in[2];
    const float* features2 = (const float*)d_in[3];
    const float* skipf     = (const float*)d_in[4];
    const float* W1  = (const float*)d_in[5];
    const float* b1  = (const float*)d_in[6];
    const float* g1  = (const float*)d_in[7];
    const float* be1 = (const float*)d_in[8];
    const float* W2  = (const float*)d_in[9];
    const float* b2  = (const float*)d_in[10];
    const float* g2  = (const float*)d_in[11];
    const float* be2 = (const float*)d_in[12];
    float* out = (float*)d_out;

    char* ws = (char*)d_ws;
    float*    s1  = (float*)(ws + 0);
    float*    q1  = (float*)(ws + 1024);
    float*    s2  = (float*)(ws + 2048);
    float*    q2  = (float*)(ws + 3072);
    int*      ind = (int*)(ws + 4096);                 // 393216 B
    float*    wgt = (float*)(ws + 397312);             // 393216 B
    ushort_t* x   = (ushort_t*)(ws + 790528);          // bf16 32768x192 (12.6 MB used)
    ushort_t* y1b = (ushort_t*)(ws + 30150656);        // 16,777,216 B (bf16 raw y1)
    ushort_t* W1b = (ushort_t*)(ws + 63705088);        // 229,376 B
    ushort_t* W2b = (ushort_t*)(ws + 63934464);        // 131,072 B
    ushort_t* f1t = (ushort_t*)(ws + 64065536);        // 4,194,304 B (bf16 8x1024x256)
    ushort_t* y2b = x;                                 // alias: x2 dead after gemm1

    hipMemsetAsync(ws, 0, 4096, stream);               // zero BN stats

    fused_pre<<<dim3(3520), dim3(256), 0, stream>>>(points1, points2, ind, wgt,
                                                    features1, features2, skipf,
                                                    W1, W2, f1t, x, W1b, W2b);

    gemm1_fused<<<dim3(ROWS_ / 64), dim3(256), 0, stream>>>(f1t, ind, wgt, x,
                                                            W1b, b1, y1b, s1, q1);
    gemm2_fused<<<dim3(ROWS_ / 128 * 4), dim3(256), 0, stream>>>(y1b, W2b, b2, s1, q1, g1, be1, y2b, s2, q2);
    bn_out_kernel<<<dim3(2048), dim3(256), 0, stream>>>(y2b, s2, q2, g2, be2, out);
}